// Round 2
// baseline (1074.058 us; speedup 1.0000x reference)
//
#include <hip/hip_runtime.h>

// ALSH masked linear: out[B,N] = x @ (W * mask)^T, mask from bucket match.
// B=2048, D=2048, N=32768, M_AUG=5, TABLE=64, R=4.0, U=0.83.
// Mask is ~all-N -> dense bf16 GEMM.
// R3: - XCD swizzle REVERTED (R2 post-mortem: default round-robin gives L3
//       broadcast of shared wb panels; disjoint-per-XCD ranges killed it).
//     - GEMM rewritten as 256x256 8-phase counted-vmcnt schedule (T2+T3+T4+T5):
//       raw s_barrier (no vmcnt(0) drain), vmcnt(4) at phases 3/7 only,
//       st_16x32 LDS swizzle via pre-swizzled global source + swizzled ds_read.
//     - maxred fused into rowstats (atomicMax on double bits, ss >= 0).

#define D_DIM 2048
#define N_ROWS 32768
#define B_ROWS 2048
#define M_AUG_C 5
#define TBL 64
#define RBIN 4.0
#define USC 0.83

typedef short bf16x8 __attribute__((ext_vector_type(8)));
typedef float f32x4 __attribute__((ext_vector_type(4)));

// ---- workspace layout (bytes) ----
#define WS_ROWSUMSQ 0                       // double[N]      256 KB
#define WS_ROWDOTA  262144                  // double[N]      256 KB
#define WS_PARTIAL  524288                  // double[16*D]   256 KB
#define WS_MAXSS    786432                  // double
#define WS_QBUCKET  786440                  // int
#define WS_COUNT    786444                  // int
#define WS_LIST     786448                  // int[N]         128 KB
#define WS_MASKF    917520                  // float[N]       128 KB
#define WS_FLAGS    1048592                 // int[256]       1 KB
#define WS_XB       1114112                 // bf16[B*D]      8 MB
#define WS_WB       9502720                 // bf16[N*D]      128 MB
#define WS_A_NEED   143720448ull            // end of WB

__device__ __forceinline__ unsigned short f2bf(float f) {
    unsigned int u = __builtin_bit_cast(unsigned int, f);
    u += 0x7fffu + ((u >> 16) & 1u);   // round-to-nearest-even
    return (unsigned short)(u >> 16);
}

typedef const __attribute__((address_space(1))) unsigned int* as1_u32p;
typedef __attribute__((address_space(3))) unsigned int* as3_u32p;

__device__ __forceinline__ void gload16(const unsigned short* g, unsigned short* l) {
    __builtin_amdgcn_global_load_lds((as1_u32p)(const void*)g, (as3_u32p)(void*)l,
                                     16, 0, 0);
}

// ---- Kernel A: per-row sum(W^2), dot(W_row, a[:D]) (fp64), bf16(W) emit,
// and global max(sumsq) via atomicMax on the positive-double bit pattern. ----
__global__ void rowstats_kernel(const float* __restrict__ W,
                                const float* __restrict__ a,
                                double* __restrict__ rowSumSq,
                                double* __restrict__ rowDotA,
                                unsigned long long* __restrict__ maxSSbits,
                                unsigned short* __restrict__ wb) {
    int wave = threadIdx.x >> 6;
    int lane = threadIdx.x & 63;
    int row  = blockIdx.x * 4 + wave;
    const float* wr = W + (size_t)row * D_DIM;
    unsigned short* wbr = wb ? wb + (size_t)row * D_DIM : (unsigned short*)0;
    double ss = 0.0, da = 0.0;
#pragma unroll
    for (int c = 0; c < 8; ++c) {
        int off = c * 256 + lane * 4;
        float4 v  = *(const float4*)(wr + off);
        float4 av = *(const float4*)(a + off);
        ss += (double)v.x * v.x + (double)v.y * v.y + (double)v.z * v.z + (double)v.w * v.w;
        da += (double)v.x * av.x + (double)v.y * av.y + (double)v.z * av.z + (double)v.w * av.w;
        if (wbr) {
            ushort4 p;
            p.x = f2bf(v.x); p.y = f2bf(v.y); p.z = f2bf(v.z); p.w = f2bf(v.w);
            *(ushort4*)(wbr + off) = p;
        }
    }
    for (int off = 32; off > 0; off >>= 1) {
        ss += __shfl_down(ss, off);
        da += __shfl_down(da, off);
    }
    if (lane == 0) {
        rowSumSq[row] = ss; rowDotA[row] = da;
        // ss >= 0 -> IEEE order == unsigned integer order on the bit pattern
        atomicMax(maxSSbits, (unsigned long long)__double_as_longlong(ss));
    }
}

// ---- Kernel C1: partial column sums of x ----
__global__ void colsum_kernel(const float* __restrict__ x,
                              double* __restrict__ partial) {
    int col   = blockIdx.x * 256 + threadIdx.x;
    int chunk = blockIdx.y;
    const float* xp = x + (size_t)chunk * 128 * D_DIM + col;
    double s = 0.0;
#pragma unroll 8
    for (int b = 0; b < 128; ++b) s += (double)xp[(size_t)b * D_DIM];
    partial[(size_t)chunk * D_DIM + col] = s;
}

// ---- Kernel C2: finish column sums, compute query bucket ----
__global__ void qhash_kernel(const double* __restrict__ partial,
                             const float* __restrict__ a,
                             int* __restrict__ qBucket) {
    __shared__ double s_ssq[256], s_dta[256];
    int tid = threadIdx.x;
    double ssq = 0.0, dta = 0.0;
    for (int c = tid; c < D_DIM; c += 256) {
        double cs = 0.0;
#pragma unroll
        for (int k = 0; k < 16; ++k) cs += partial[(size_t)k * D_DIM + c];
        ssq += cs * cs;
        dta += cs * (double)a[c];
    }
    s_ssq[tid] = ssq; s_dta[tid] = dta;
    __syncthreads();
    for (int s = 128; s > 0; s >>= 1) {
        if (tid < s) { s_ssq[tid] += s_ssq[tid + s]; s_dta[tid] += s_dta[tid + s]; }
        __syncthreads();
    }
    if (tid == 0) {
        double dq = s_dta[0] / sqrt(s_ssq[0]);
        double aug = 0.0;
        for (int i = 0; i < M_AUG_C; ++i) aug += 0.5 * (double)a[D_DIM + i];
        double h = floor((dq + aug) / RBIN);
        double m = fmod(h, (double)TBL);
        if (m < 0.0) m += (double)TBL;
        *qBucket = (int)m;
    }
}

// ---- Kernel D: row buckets vs query; emit mask float, tile flags, compact list ----
__global__ void mask_kernel(const double* __restrict__ rowSumSq,
                            const double* __restrict__ rowDotA,
                            const double* __restrict__ maxSS,
                            const int* __restrict__ qBucket,
                            const float* __restrict__ a,
                            int* __restrict__ count,
                            int* __restrict__ list,
                            float* __restrict__ maskF,
                            int* __restrict__ flags) {
    int n = blockIdx.x * 256 + threadIdx.x;
    double s  = USC / sqrt(*maxSS);
    double n2 = s * s * rowSumSq[n];
    double acc = s * rowDotA[n];
    double p = n2;
#pragma unroll
    for (int i = 0; i < M_AUG_C; ++i) {    // powers n2^(2^i), successive squaring
        acc += p * (double)a[D_DIM + i];
        p = p * p;
    }
    double h = floor(acc / RBIN);
    double m = fmod(h, (double)TBL);
    if (m < 0.0) m += (double)TBL;
    bool active = ((int)m == *qBucket);
    maskF[n] = active ? 1.f : 0.f;
    if (active) {
        int pos = atomicAdd(count, 1);
        list[pos] = n;
        atomicOr(&flags[n >> 7], 1);
    }
}

// ---- Kernel E2: x -> bf16 ----
__global__ void convx_kernel(const float* __restrict__ x,
                             unsigned short* __restrict__ xb) {
    size_t e = ((size_t)blockIdx.x * 256 + threadIdx.x) * 8;
    float4 v0 = *(const float4*)(x + e);
    float4 v1 = *(const float4*)(x + e + 4);
    ushort4 p0, p1;
    p0.x = f2bf(v0.x); p0.y = f2bf(v0.y); p0.z = f2bf(v0.z); p0.w = f2bf(v0.w);
    p1.x = f2bf(v1.x); p1.y = f2bf(v1.y); p1.z = f2bf(v1.z); p1.w = f2bf(v1.w);
    *(ushort4*)(xb + e)     = p0;
    *(ushort4*)(xb + e + 4) = p1;
}

// ======== Kernel F-A: 256x256 8-phase counted-vmcnt bf16 GEMM ========
// 8 waves (2M x 4N), BK=64, two K-tiles per 8-phase iteration.
// LDS: [parity][op A/B][half 128 rows][128 rows x 64 cols bf16] = 128 KiB.
// st_16x32 swizzle (byte ^= (row&4)<<3): linear LDS dest for global_load_lds,
// permutation pre-applied to the per-lane GLOBAL source, re-applied on ds_read.
// Raw s_barrier everywhere (no vmcnt drain); vmcnt(4) at phases 3 and 7 only.

#define BAR() do { asm volatile("" ::: "memory"); \
                   __builtin_amdgcn_s_barrier(); \
                   asm volatile("" ::: "memory"); } while (0)
#define LGKM0() do { asm volatile("s_waitcnt lgkmcnt(0)" ::: "memory"); \
                     __builtin_amdgcn_sched_barrier(0); } while (0)
#define VM4() asm volatile("s_waitcnt vmcnt(4)" ::: "memory")
#define VM0() asm volatile("s_waitcnt vmcnt(0)" ::: "memory")
#define VM8() asm volatile("s_waitcnt vmcnt(8)" ::: "memory")

#define READ_A(P, MH) do { _Pragma("unroll") \
    for (int mi = 0; mi < 4; ++mi) { \
        aF[mi][0] = *(const bf16x8*)(aB##P + ((MH)*4 + mi) * 1024 + kLo); \
        aF[mi][1] = *(const bf16x8*)(aB##P + ((MH)*4 + mi) * 1024 + kLo + 32); } } while (0)

#define READ_B(P, NH) do { _Pragma("unroll") \
    for (int nf = 0; nf < 2; ++nf) { \
        bF[(NH)*2 + nf][0] = *(const bf16x8*)(bB##P + ((NH)*2 + nf) * 1024 + kLo); \
        bF[(NH)*2 + nf][1] = *(const bf16x8*)(bB##P + ((NH)*2 + nf) * 1024 + kLo + 32); } } while (0)

#define STAGE_A(P, H, T) do { \
    gload16(xg0 + (size_t)((H)*128    ) * D_DIM + (T)*64, &lds[P][0][H][wid*1024      ]); \
    gload16(xg0 + (size_t)((H)*128 + 8) * D_DIM + (T)*64, &lds[P][0][H][wid*1024 + 512]); } while (0)

#define STAGE_B(P, H, T) do { \
    gload16(wg0 + (size_t)((H)*128    ) * D_DIM + (T)*64, &lds[P][1][H][wid*1024      ]); \
    gload16(wg0 + (size_t)((H)*128 + 8) * D_DIM + (T)*64, &lds[P][1][H][wid*1024 + 512]); } while (0)

#define MFMA_Q(MH, NH) do { _Pragma("unroll") \
    for (int mi = 0; mi < 4; ++mi) { _Pragma("unroll") \
    for (int nf = 0; nf < 2; ++nf) { _Pragma("unroll") \
    for (int kb = 0; kb < 2; ++kb) { \
        acc[(MH)*4 + mi][(NH)*2 + nf] = __builtin_amdgcn_mfma_f32_16x16x32_bf16( \
            aF[mi][kb], bF[(NH)*2 + nf][kb], acc[(MH)*4 + mi][(NH)*2 + nf], 0, 0, 0); \
    } } } } while (0)

__launch_bounds__(512, 2)
__global__ void gemm_256(const unsigned short* __restrict__ xb,
                         const unsigned short* __restrict__ wb,
                         const int* __restrict__ flags,
                         const float* __restrict__ maskF,
                         float* __restrict__ out) {
    int bRow0 = blockIdx.x * 256;
    int nRow0 = blockIdx.y * 256;
    int tid = threadIdx.x;

    if ((flags[blockIdx.y * 2] | flags[blockIdx.y * 2 + 1]) == 0) {
#pragma unroll
        for (int i = 0; i < 32; ++i) {
            int idx = tid + i * 512;
            int r = idx >> 6, c = idx & 63;
            *(float4*)(out + (size_t)(bRow0 + r) * N_ROWS + nRow0 + c * 4) =
                float4{0.f, 0.f, 0.f, 0.f};
        }
        return;
    }

    __shared__ __align__(16) unsigned short lds[2][2][2][128 * 64];  // 128 KiB

    int wid  = tid >> 6, lane = tid & 63;
    int l16  = lane & 15, quad = lane >> 4;
    int wm   = wid >> 2,  wn   = wid & 3;

    // staging: lane l of call c writes LDS linear (wid*2+c)*1024B + l*16B
    //   -> dest row (wid*2+c)*8 + l/8, col (l&7)*16B.  Source pre-swizzled:
    //   gcol = ((l&7)*16) ^ ((row&4)<<3), with row&4 = (l&32)>>3.
    int srow8 = lane >> 3;
    int gcolb = ((lane & 7) * 16) ^ (lane & 32);
    const unsigned short* xg0 = xb + (size_t)(bRow0 + wid * 16 + srow8) * D_DIM + (gcolb >> 1);
    const unsigned short* wg0 = wb + (size_t)(nRow0 + wid * 16 + srow8) * D_DIM + (gcolb >> 1);

    // fragment-read bases (shorts); swizzle on read: koff ^= (row&4)<<3, row&4 = l16&4
    const unsigned short* aB0 = &lds[0][0][wm][0] + l16 * 64;
    const unsigned short* aB1 = &lds[1][0][wm][0] + l16 * 64;
    const unsigned short* bB0 = &lds[0][1][wn >> 1][0] + (wn & 1) * 4096 + l16 * 64;
    const unsigned short* bB1 = &lds[1][1][wn >> 1][0] + (wn & 1) * 4096 + l16 * 64;
    const int kLo = ((quad * 16) ^ ((l16 & 4) << 3)) >> 1;   // shorts

    f32x4 acc[8][4];
#pragma unroll
    for (int mi = 0; mi < 8; ++mi)
#pragma unroll
        for (int nf = 0; nf < 4; ++nf)
            acc[mi][nf] = (f32x4){0.f, 0.f, 0.f, 0.f};

    bf16x8 aF[4][2], bF[4][2];

    // ---- prologue: stage tiles 0 (parity 0) and 1 (parity 1); tile0 ready ----
    STAGE_A(0, 0, 0); STAGE_A(0, 1, 0); STAGE_B(0, 0, 0); STAGE_B(0, 1, 0);
    STAGE_A(1, 0, 1); STAGE_A(1, 1, 1); STAGE_B(1, 0, 1); STAGE_B(1, 1, 1);
    VM8();
    BAR();

    // ---- main: 16 iterations x (2 K-tiles, 8 phases). NT = 32 K-tiles. ----
#pragma unroll 1
    for (int i = 0; i < 16; ++i) {
        const int t1 = 2 * i + 1;
        const int u0 = 2 * i + 2;   // staged this iter, parity 0
        const int u1 = 2 * i + 3;   // staged this iter, parity 1

        // φ0: tile t0 Q(0,0); reads A0.mh0 + B0.nh0; stage A(t1).h0
        READ_A(0, 0);
        READ_B(0, 0);
        if (i > 0) STAGE_A(1, 0, t1);
        BAR(); LGKM0();
        __builtin_amdgcn_s_setprio(1); MFMA_Q(0, 0); __builtin_amdgcn_s_setprio(0);
        BAR();
        // φ1: Q(0,1); reads B0.nh1; stage A(t1).h1
        READ_B(0, 1);
        if (i > 0) STAGE_A(1, 1, t1);
        BAR(); LGKM0();
        __builtin_amdgcn_s_setprio(1); MFMA_Q(0, 1); __builtin_amdgcn_s_setprio(0);
        BAR();
        // φ2: Q(1,1); reads A0.mh1; stage B(u0).h0
        READ_A(0, 1);
        if (i < 15) STAGE_B(0, 0, u0);
        BAR(); LGKM0();
        __builtin_amdgcn_s_setprio(1); MFMA_Q(1, 1); __builtin_amdgcn_s_setprio(0);
        BAR();
        // φ3: Q(1,0); stage B(u0).h1; counted vmcnt
        if (i < 15) STAGE_B(0, 1, u0);
        BAR(); LGKM0();
        __builtin_amdgcn_s_setprio(1); MFMA_Q(1, 0); __builtin_amdgcn_s_setprio(0);
        if (i < 15) { VM4(); } else { VM0(); }
        BAR();
        // φ4: tile t1 Q(0,0); reads A1.mh0 + B1.nh0; stage A(u0).h0
        READ_A(1, 0);
        READ_B(1, 0);
        if (i < 15) STAGE_A(0, 0, u0);
        BAR(); LGKM0();
        __builtin_amdgcn_s_setprio(1); MFMA_Q(0, 0); __builtin_amdgcn_s_setprio(0);
        BAR();
        // φ5: Q(0,1); reads B1.nh1; stage A(u0).h1
        READ_B(1, 1);
        if (i < 15) STAGE_A(0, 1, u0);
        BAR(); LGKM0();
        __builtin_amdgcn_s_setprio(1); MFMA_Q(0, 1); __builtin_amdgcn_s_setprio(0);
        BAR();
        // φ6: Q(1,1); reads A1.mh1; stage B(u1).h0
        READ_A(1, 1);
        if (i < 15) STAGE_B(1, 0, u1);
        BAR(); LGKM0();
        __builtin_amdgcn_s_setprio(1); MFMA_Q(1, 1); __builtin_amdgcn_s_setprio(0);
        BAR();
        // φ7: Q(1,0); stage B(u1).h1; counted vmcnt
        if (i < 15) STAGE_B(1, 1, u1);
        BAR(); LGKM0();
        __builtin_amdgcn_s_setprio(1); MFMA_Q(1, 0); __builtin_amdgcn_s_setprio(0);
        if (i < 15) { VM4(); }
        BAR();
    }

    // epilogue: C/D layout col=l16 (n), row=quad*4+reg (b); scale by mask[col]
#pragma unroll
    for (int nf = 0; nf < 4; ++nf) {
        int col = nRow0 + wn * 64 + nf * 16 + l16;
        float mv = maskF[col];
#pragma unroll
        for (int mi = 0; mi < 8; ++mi) {
            int rbase = bRow0 + wm * 128 + mi * 16 + quad * 4;
#pragma unroll
            for (int r = 0; r < 4; ++r)
                out[(size_t)(rbase + r) * N_ROWS + col] = acc[mi][nf][r] * mv;
        }
    }
}

// ---- Kernel F-B (fallback, small ws): compacted-list GEMM from R1 ----
__launch_bounds__(256, 2)
__global__ void gemm_kernel(const float* __restrict__ x,
                            const float* __restrict__ W,
                            const int* __restrict__ count,
                            const int* __restrict__ list,
                            float* __restrict__ out) {
    int cnt = *count;
    int jBase = blockIdx.y * 64;
    if (jBase >= cnt) return;
    int bRow0 = blockIdx.x * 128;

    __shared__ short xT[128 * 80];
    __shared__ short wT[64 * 80];

    int tid  = threadIdx.x;
    int wave = tid >> 6, lane = tid & 63;
    int quad = lane >> 4, l16 = lane & 15;

    int wrow_ids[4];
#pragma unroll
    for (int i = 0; i < 4; ++i) {
        int idx = tid + i * 256;
        int j = jBase + (idx >> 4);
        wrow_ids[i] = list[j < cnt ? j : (cnt - 1)];
    }

    f32x4 acc[2][4];
#pragma unroll
    for (int mi = 0; mi < 2; ++mi)
#pragma unroll
        for (int nf = 0; nf < 4; ++nf)
            acc[mi][nf] = (f32x4){0.f, 0.f, 0.f, 0.f};

    for (int k0 = 0; k0 < D_DIM; k0 += 64) {
        __syncthreads();
#pragma unroll
        for (int i = 0; i < 8; ++i) {
            int idx = tid + i * 256;
            int r = idx >> 4, kq = idx & 15;
            float4 v = *(const float4*)(x + (size_t)(bRow0 + r) * D_DIM + k0 + kq * 4);
            ushort4 b;
            b.x = f2bf(v.x); b.y = f2bf(v.y); b.z = f2bf(v.z); b.w = f2bf(v.w);
            *(ushort4*)(&xT[r * 80 + kq * 4]) = b;
        }
#pragma unroll
        for (int i = 0; i < 4; ++i) {
            int idx = tid + i * 256;
            int r = idx >> 4, kq = idx & 15;
            float4 v = *(const float4*)(W + (size_t)wrow_ids[i] * D_DIM + k0 + kq * 4);
            ushort4 b;
            b.x = f2bf(v.x); b.y = f2bf(v.y); b.z = f2bf(v.z); b.w = f2bf(v.w);
            *(ushort4*)(&wT[r * 80 + kq * 4]) = b;
        }
        __syncthreads();
#pragma unroll
        for (int kk = 0; kk < 64; kk += 32) {
            bf16x8 a0 = *(const bf16x8*)(&xT[(wave * 32 + l16) * 80 + kk + quad * 8]);
            bf16x8 a1 = *(const bf16x8*)(&xT[(wave * 32 + 16 + l16) * 80 + kk + quad * 8]);
#pragma unroll
            for (int nf = 0; nf < 4; ++nf) {
                bf16x8 bv = *(const bf16x8*)(&wT[(nf * 16 + l16) * 80 + kk + quad * 8]);
                acc[0][nf] = __builtin_amdgcn_mfma_f32_16x16x32_bf16(a0, bv, acc[0][nf], 0, 0, 0);
                acc[1][nf] = __builtin_amdgcn_mfma_f32_16x16x32_bf16(a1, bv, acc[1][nf], 0, 0, 0);
            }
        }
    }

#pragma unroll
    for (int nf = 0; nf < 4; ++nf) {
        int j = jBase + nf * 16 + l16;
        if (j < cnt) {
            int col = list[j];
#pragma unroll
            for (int mi = 0; mi < 2; ++mi) {
                int rbase = bRow0 + wave * 32 + mi * 16 + quad * 4;
#pragma unroll
                for (int r = 0; r < 4; ++r)
                    out[(size_t)(rbase + r) * N_ROWS + col] = acc[mi][nf][r];
            }
        }
    }
}

extern "C" void kernel_launch(void* const* d_in, const int* in_sizes, int n_in,
                              void* d_out, int out_size, void* d_ws, size_t ws_size,
                              hipStream_t stream) {
    const float* x = (const float*)d_in[0];
    const float* W = (const float*)d_in[1];
    const float* a = (const float*)d_in[2];
    float* out = (float*)d_out;
    char* ws = (char*)d_ws;

    double* rowSumSq = (double*)(ws + WS_ROWSUMSQ);
    double* rowDotA  = (double*)(ws + WS_ROWDOTA);
    double* partial  = (double*)(ws + WS_PARTIAL);
    double* maxSS    = (double*)(ws + WS_MAXSS);
    int*    qBucket  = (int*)(ws + WS_QBUCKET);
    int*    count    = (int*)(ws + WS_COUNT);
    int*    list     = (int*)(ws + WS_LIST);
    float*  maskF    = (float*)(ws + WS_MASKF);
    int*    flags    = (int*)(ws + WS_FLAGS);
    unsigned short* xb = (unsigned short*)(ws + WS_XB);
    unsigned short* wb = (unsigned short*)(ws + WS_WB);

    bool pathA = (ws_size >= WS_A_NEED);

    hipMemsetAsync(count, 0, sizeof(int), stream);
    hipMemsetAsync(flags, 0, 256 * sizeof(int), stream);
    hipMemsetAsync(maxSS, 0, sizeof(double), stream);   // +0.0 bits, ss >= 0

    // Single pass over W: stats + bf16 emit + running max (fused maxred).
    rowstats_kernel<<<N_ROWS / 4, 256, 0, stream>>>(
        W, a, rowSumSq, rowDotA, (unsigned long long*)maxSS,
        pathA ? wb : (unsigned short*)0);
    colsum_kernel<<<dim3(D_DIM / 256, 16), 256, 0, stream>>>(x, partial);
    qhash_kernel<<<1, 256, 0, stream>>>(partial, a, qBucket);
    mask_kernel<<<N_ROWS / 256, 256, 0, stream>>>(rowSumSq, rowDotA, maxSS, qBucket,
                                                  a, count, list, maskF, flags);

    if (pathA) {
        convx_kernel<<<(B_ROWS * (D_DIM / 8)) / 256, 256, 0, stream>>>(x, xb);
        gemm_256<<<dim3(B_ROWS / 256, N_ROWS / 256), 512, 0, stream>>>(
            xb, wb, flags, maskF, out);
    } else {
        // Path B: R1 fallback (fused-conversion compacted GEMM).
        hipMemsetAsync(out, 0, (size_t)out_size * sizeof(float), stream);
        gemm_kernel<<<dim3(B_ROWS / 128, N_ROWS / 64), 256, 0, stream>>>(x, W, count, list, out);
    }
}

// Round 3
// 787.709 us; speedup vs baseline: 1.3635x; 1.3635x over previous
//
#include <hip/hip_runtime.h>

// ALSH masked linear: out[B,N] = x @ (W * mask)^T, mask from bucket match.
// B=2048, D=2048, N=32768, M_AUG=5, TABLE=64, R=4.0, U=0.83.
// Mask is ~all-N -> dense bf16 GEMM (256x256 8-phase counted-vmcnt, R3).
// R4: - rowstats atomicMax REVERTED (R3 post-mortem: 32768 same-address
//       atomics serialized -> 398 us). maxred restored as 32-block kernel
//       (32 atomics total).
//     - rowstats: 2 rows/wave -> 2x memory-level parallelism (was 8x16B
//       in flight per wave = latency-bound at 679 GB/s).
//     - colsum: fp64 atomicAdd per column (16-way contention, fine);
//       qhash now reads 16 KB not 256 KB.
//     - gemm_256 FROZEN this round (no counters for it in R3; get evidence
//       first).

#define D_DIM 2048
#define N_ROWS 32768
#define B_ROWS 2048
#define M_AUG_C 5
#define TBL 64
#define RBIN 4.0
#define USC 0.83

typedef short bf16x8 __attribute__((ext_vector_type(8)));
typedef float f32x4 __attribute__((ext_vector_type(4)));

// ---- workspace layout (bytes) ----
#define WS_ROWSUMSQ 0                       // double[N]      256 KB
#define WS_ROWDOTA  262144                  // double[N]      256 KB
#define WS_PARTIAL  524288                  // double[D]      16 KB (colsums)
#define WS_MAXSS    786432                  // double
#define WS_QBUCKET  786440                  // int
#define WS_COUNT    786444                  // int
#define WS_LIST     786448                  // int[N]         128 KB
#define WS_MASKF    917520                  // float[N]       128 KB
#define WS_FLAGS    1048592                 // int[256]       1 KB
#define WS_XB       1114112                 // bf16[B*D]      8 MB
#define WS_WB       9502720                 // bf16[N*D]      128 MB
#define WS_A_NEED   143720448ull            // end of WB

__device__ __forceinline__ unsigned short f2bf(float f) {
    unsigned int u = __builtin_bit_cast(unsigned int, f);
    u += 0x7fffu + ((u >> 16) & 1u);   // round-to-nearest-even
    return (unsigned short)(u >> 16);
}

typedef const __attribute__((address_space(1))) unsigned int* as1_u32p;
typedef __attribute__((address_space(3))) unsigned int* as3_u32p;

__device__ __forceinline__ void gload16(const unsigned short* g, unsigned short* l) {
    __builtin_amdgcn_global_load_lds((as1_u32p)(const void*)g, (as3_u32p)(void*)l,
                                     16, 0, 0);
}

// ---- Kernel A: per-row sum(W^2), dot(W_row, a[:D]) (fp64), bf16(W) emit.
// 2 rows per wave for 2x in-flight loads (R3 was latency-bound at 679 GB/s).
__global__ void rowstats_kernel(const float* __restrict__ W,
                                const float* __restrict__ a,
                                double* __restrict__ rowSumSq,
                                double* __restrict__ rowDotA,
                                unsigned short* __restrict__ wb) {
    int wave = threadIdx.x >> 6;
    int lane = threadIdx.x & 63;
    int row0 = blockIdx.x * 8 + wave * 2;
    const float* wr0 = W + (size_t)row0 * D_DIM;
    const float* wr1 = wr0 + D_DIM;
    unsigned short* wb0 = wb ? wb + (size_t)row0 * D_DIM : (unsigned short*)0;
    double ss0 = 0.0, da0 = 0.0, ss1 = 0.0, da1 = 0.0;
#pragma unroll
    for (int c = 0; c < 8; ++c) {
        int off = c * 256 + lane * 4;
        float4 v0 = *(const float4*)(wr0 + off);
        float4 v1 = *(const float4*)(wr1 + off);
        float4 av = *(const float4*)(a + off);
        ss0 += (double)v0.x * v0.x + (double)v0.y * v0.y + (double)v0.z * v0.z + (double)v0.w * v0.w;
        da0 += (double)v0.x * av.x + (double)v0.y * av.y + (double)v0.z * av.z + (double)v0.w * av.w;
        ss1 += (double)v1.x * v1.x + (double)v1.y * v1.y + (double)v1.z * v1.z + (double)v1.w * v1.w;
        da1 += (double)v1.x * av.x + (double)v1.y * av.y + (double)v1.z * av.z + (double)v1.w * av.w;
        if (wb0) {
            ushort4 p0, p1;
            p0.x = f2bf(v0.x); p0.y = f2bf(v0.y); p0.z = f2bf(v0.z); p0.w = f2bf(v0.w);
            p1.x = f2bf(v1.x); p1.y = f2bf(v1.y); p1.z = f2bf(v1.z); p1.w = f2bf(v1.w);
            *(ushort4*)(wb0 + off)         = p0;
            *(ushort4*)(wb0 + D_DIM + off) = p1;
        }
    }
    for (int off = 32; off > 0; off >>= 1) {
        ss0 += __shfl_down(ss0, off);
        da0 += __shfl_down(da0, off);
        ss1 += __shfl_down(ss1, off);
        da1 += __shfl_down(da1, off);
    }
    if (lane == 0) {
        rowSumSq[row0]     = ss0; rowDotA[row0]     = da0;
        rowSumSq[row0 + 1] = ss1; rowDotA[row0 + 1] = da1;
    }
}

// ---- Kernel B: max over rowSumSq. 32 blocks, one atomicMax each (ss >= 0,
// so IEEE order == unsigned-int order on the bit pattern). ----
__global__ void maxred_kernel(const double* __restrict__ rowSumSq,
                              unsigned long long* __restrict__ maxBits) {
    int i = blockIdx.x * 1024 + threadIdx.x;
    double m = rowSumSq[i];
    for (int off = 32; off > 0; off >>= 1) m = fmax(m, __shfl_down(m, off));
    __shared__ double sm[16];
    int wave = threadIdx.x >> 6, lane = threadIdx.x & 63;
    if (lane == 0) sm[wave] = m;
    __syncthreads();
    if (threadIdx.x == 0) {
        double mm = sm[0];
#pragma unroll
        for (int k = 1; k < 16; ++k) mm = fmax(mm, sm[k]);
        atomicMax(maxBits, (unsigned long long)__double_as_longlong(mm));
    }
}

// ---- Kernel C1: column sums of x via fp64 atomicAdd (16-way contention) ----
__global__ void colsum_kernel(const float* __restrict__ x,
                              double* __restrict__ colsumD) {
    int col   = blockIdx.x * 256 + threadIdx.x;
    int chunk = blockIdx.y;
    const float* xp = x + (size_t)chunk * 128 * D_DIM + col;
    double s = 0.0;
#pragma unroll 8
    for (int b = 0; b < 128; ++b) s += (double)xp[(size_t)b * D_DIM];
    atomicAdd(&colsumD[col], s);
}

// ---- Kernel C2: query bucket from finished column sums (16 KB read) ----
__global__ void qhash_kernel(const double* __restrict__ colsumD,
                             const float* __restrict__ a,
                             int* __restrict__ qBucket) {
    __shared__ double s_ssq[256], s_dta[256];
    int tid = threadIdx.x;
    double ssq = 0.0, dta = 0.0;
    for (int c = tid; c < D_DIM; c += 256) {
        double cs = colsumD[c];
        ssq += cs * cs;
        dta += cs * (double)a[c];
    }
    s_ssq[tid] = ssq; s_dta[tid] = dta;
    __syncthreads();
    for (int s = 128; s > 0; s >>= 1) {
        if (tid < s) { s_ssq[tid] += s_ssq[tid + s]; s_dta[tid] += s_dta[tid + s]; }
        __syncthreads();
    }
    if (tid == 0) {
        double dq = s_dta[0] / sqrt(s_ssq[0]);
        double aug = 0.0;
        for (int i = 0; i < M_AUG_C; ++i) aug += 0.5 * (double)a[D_DIM + i];
        double h = floor((dq + aug) / RBIN);
        double m = fmod(h, (double)TBL);
        if (m < 0.0) m += (double)TBL;
        *qBucket = (int)m;
    }
}

// ---- Kernel D: row buckets vs query; emit mask float, tile flags, compact list ----
__global__ void mask_kernel(const double* __restrict__ rowSumSq,
                            const double* __restrict__ rowDotA,
                            const double* __restrict__ maxSS,
                            const int* __restrict__ qBucket,
                            const float* __restrict__ a,
                            int* __restrict__ count,
                            int* __restrict__ list,
                            float* __restrict__ maskF,
                            int* __restrict__ flags) {
    int n = blockIdx.x * 256 + threadIdx.x;
    double s  = USC / sqrt(*maxSS);
    double n2 = s * s * rowSumSq[n];
    double acc = s * rowDotA[n];
    double p = n2;
#pragma unroll
    for (int i = 0; i < M_AUG_C; ++i) {    // powers n2^(2^i), successive squaring
        acc += p * (double)a[D_DIM + i];
        p = p * p;
    }
    double h = floor(acc / RBIN);
    double m = fmod(h, (double)TBL);
    if (m < 0.0) m += (double)TBL;
    bool active = ((int)m == *qBucket);
    maskF[n] = active ? 1.f : 0.f;
    if (active) {
        int pos = atomicAdd(count, 1);
        list[pos] = n;
        atomicOr(&flags[n >> 7], 1);
    }
}

// ---- Kernel E2: x -> bf16 ----
__global__ void convx_kernel(const float* __restrict__ x,
                             unsigned short* __restrict__ xb) {
    size_t e = ((size_t)blockIdx.x * 256 + threadIdx.x) * 8;
    float4 v0 = *(const float4*)(x + e);
    float4 v1 = *(const float4*)(x + e + 4);
    ushort4 p0, p1;
    p0.x = f2bf(v0.x); p0.y = f2bf(v0.y); p0.z = f2bf(v0.z); p0.w = f2bf(v0.w);
    p1.x = f2bf(v1.x); p1.y = f2bf(v1.y); p1.z = f2bf(v1.z); p1.w = f2bf(v1.w);
    *(ushort4*)(xb + e)     = p0;
    *(ushort4*)(xb + e + 4) = p1;
}

// ======== Kernel F-A: 256x256 8-phase counted-vmcnt bf16 GEMM (FROZEN) ========
// 8 waves (2M x 4N), BK=64, two K-tiles per 8-phase iteration.
// LDS: [parity][op A/B][half 128 rows][128 rows x 64 cols bf16] = 128 KiB.
// st_16x32 swizzle (byte ^= (row&4)<<3): linear LDS dest for global_load_lds,
// permutation pre-applied to the per-lane GLOBAL source, re-applied on ds_read.
// Raw s_barrier everywhere (no vmcnt drain); vmcnt(4) at phases 3 and 7 only.

#define BAR() do { asm volatile("" ::: "memory"); \
                   __builtin_amdgcn_s_barrier(); \
                   asm volatile("" ::: "memory"); } while (0)
#define LGKM0() do { asm volatile("s_waitcnt lgkmcnt(0)" ::: "memory"); \
                     __builtin_amdgcn_sched_barrier(0); } while (0)
#define VM4() asm volatile("s_waitcnt vmcnt(4)" ::: "memory")
#define VM0() asm volatile("s_waitcnt vmcnt(0)" ::: "memory")
#define VM8() asm volatile("s_waitcnt vmcnt(8)" ::: "memory")

#define READ_A(P, MH) do { _Pragma("unroll") \
    for (int mi = 0; mi < 4; ++mi) { \
        aF[mi][0] = *(const bf16x8*)(aB##P + ((MH)*4 + mi) * 1024 + kLo); \
        aF[mi][1] = *(const bf16x8*)(aB##P + ((MH)*4 + mi) * 1024 + kLo + 32); } } while (0)

#define READ_B(P, NH) do { _Pragma("unroll") \
    for (int nf = 0; nf < 2; ++nf) { \
        bF[(NH)*2 + nf][0] = *(const bf16x8*)(bB##P + ((NH)*2 + nf) * 1024 + kLo); \
        bF[(NH)*2 + nf][1] = *(const bf16x8*)(bB##P + ((NH)*2 + nf) * 1024 + kLo + 32); } } while (0)

#define STAGE_A(P, H, T) do { \
    gload16(xg0 + (size_t)((H)*128    ) * D_DIM + (T)*64, &lds[P][0][H][wid*1024      ]); \
    gload16(xg0 + (size_t)((H)*128 + 8) * D_DIM + (T)*64, &lds[P][0][H][wid*1024 + 512]); } while (0)

#define STAGE_B(P, H, T) do { \
    gload16(wg0 + (size_t)((H)*128    ) * D_DIM + (T)*64, &lds[P][1][H][wid*1024      ]); \
    gload16(wg0 + (size_t)((H)*128 + 8) * D_DIM + (T)*64, &lds[P][1][H][wid*1024 + 512]); } while (0)

#define MFMA_Q(MH, NH) do { _Pragma("unroll") \
    for (int mi = 0; mi < 4; ++mi) { _Pragma("unroll") \
    for (int nf = 0; nf < 2; ++nf) { _Pragma("unroll") \
    for (int kb = 0; kb < 2; ++kb) { \
        acc[(MH)*4 + mi][(NH)*2 + nf] = __builtin_amdgcn_mfma_f32_16x16x32_bf16( \
            aF[mi][kb], bF[(NH)*2 + nf][kb], acc[(MH)*4 + mi][(NH)*2 + nf], 0, 0, 0); \
    } } } } while (0)

__launch_bounds__(512, 2)
__global__ void gemm_256(const unsigned short* __restrict__ xb,
                         const unsigned short* __restrict__ wb,
                         const int* __restrict__ flags,
                         const float* __restrict__ maskF,
                         float* __restrict__ out) {
    int bRow0 = blockIdx.x * 256;
    int nRow0 = blockIdx.y * 256;
    int tid = threadIdx.x;

    if ((flags[blockIdx.y * 2] | flags[blockIdx.y * 2 + 1]) == 0) {
#pragma unroll
        for (int i = 0; i < 32; ++i) {
            int idx = tid + i * 512;
            int r = idx >> 6, c = idx & 63;
            *(float4*)(out + (size_t)(bRow0 + r) * N_ROWS + nRow0 + c * 4) =
                float4{0.f, 0.f, 0.f, 0.f};
        }
        return;
    }

    __shared__ __align__(16) unsigned short lds[2][2][2][128 * 64];  // 128 KiB

    int wid  = tid >> 6, lane = tid & 63;
    int l16  = lane & 15, quad = lane >> 4;
    int wm   = wid >> 2,  wn   = wid & 3;

    // staging: lane l of call c writes LDS linear (wid*2+c)*1024B + l*16B
    //   -> dest row (wid*2+c)*8 + l/8, col (l&7)*16B.  Source pre-swizzled:
    //   gcol = ((l&7)*16) ^ ((row&4)<<3), with row&4 = (l&32)>>3.
    int srow8 = lane >> 3;
    int gcolb = ((lane & 7) * 16) ^ (lane & 32);
    const unsigned short* xg0 = xb + (size_t)(bRow0 + wid * 16 + srow8) * D_DIM + (gcolb >> 1);
    const unsigned short* wg0 = wb + (size_t)(nRow0 + wid * 16 + srow8) * D_DIM + (gcolb >> 1);

    // fragment-read bases (shorts); swizzle on read: koff ^= (row&4)<<3, row&4 = l16&4
    const unsigned short* aB0 = &lds[0][0][wm][0] + l16 * 64;
    const unsigned short* aB1 = &lds[1][0][wm][0] + l16 * 64;
    const unsigned short* bB0 = &lds[0][1][wn >> 1][0] + (wn & 1) * 4096 + l16 * 64;
    const unsigned short* bB1 = &lds[1][1][wn >> 1][0] + (wn & 1) * 4096 + l16 * 64;
    const int kLo = ((quad * 16) ^ ((l16 & 4) << 3)) >> 1;   // shorts

    f32x4 acc[8][4];
#pragma unroll
    for (int mi = 0; mi < 8; ++mi)
#pragma unroll
        for (int nf = 0; nf < 4; ++nf)
            acc[mi][nf] = (f32x4){0.f, 0.f, 0.f, 0.f};

    bf16x8 aF[4][2], bF[4][2];

    // ---- prologue: stage tiles 0 (parity 0) and 1 (parity 1); tile0 ready ----
    STAGE_A(0, 0, 0); STAGE_A(0, 1, 0); STAGE_B(0, 0, 0); STAGE_B(0, 1, 0);
    STAGE_A(1, 0, 1); STAGE_A(1, 1, 1); STAGE_B(1, 0, 1); STAGE_B(1, 1, 1);
    VM8();
    BAR();

    // ---- main: 16 iterations x (2 K-tiles, 8 phases). NT = 32 K-tiles. ----
#pragma unroll 1
    for (int i = 0; i < 16; ++i) {
        const int t1 = 2 * i + 1;
        const int u0 = 2 * i + 2;   // staged this iter, parity 0
        const int u1 = 2 * i + 3;   // staged this iter, parity 1

        // φ0: tile t0 Q(0,0); reads A0.mh0 + B0.nh0; stage A(t1).h0
        READ_A(0, 0);
        READ_B(0, 0);
        if (i > 0) STAGE_A(1, 0, t1);
        BAR(); LGKM0();
        __builtin_amdgcn_s_setprio(1); MFMA_Q(0, 0); __builtin_amdgcn_s_setprio(0);
        BAR();
        // φ1: Q(0,1); reads B0.nh1; stage A(t1).h1
        READ_B(0, 1);
        if (i > 0) STAGE_A(1, 1, t1);
        BAR(); LGKM0();
        __builtin_amdgcn_s_setprio(1); MFMA_Q(0, 1); __builtin_amdgcn_s_setprio(0);
        BAR();
        // φ2: Q(1,1); reads A0.mh1; stage B(u0).h0
        READ_A(0, 1);
        if (i < 15) STAGE_B(0, 0, u0);
        BAR(); LGKM0();
        __builtin_amdgcn_s_setprio(1); MFMA_Q(1, 1); __builtin_amdgcn_s_setprio(0);
        BAR();
        // φ3: Q(1,0); stage B(u0).h1; counted vmcnt
        if (i < 15) STAGE_B(0, 1, u0);
        BAR(); LGKM0();
        __builtin_amdgcn_s_setprio(1); MFMA_Q(1, 0); __builtin_amdgcn_s_setprio(0);
        if (i < 15) { VM4(); } else { VM0(); }
        BAR();
        // φ4: tile t1 Q(0,0); reads A1.mh0 + B1.nh0; stage A(u0).h0
        READ_A(1, 0);
        READ_B(1, 0);
        if (i < 15) STAGE_A(0, 0, u0);
        BAR(); LGKM0();
        __builtin_amdgcn_s_setprio(1); MFMA_Q(0, 0); __builtin_amdgcn_s_setprio(0);
        BAR();
        // φ5: Q(0,1); reads B1.nh1; stage A(u0).h1
        READ_B(1, 1);
        if (i < 15) STAGE_A(0, 1, u0);
        BAR(); LGKM0();
        __builtin_amdgcn_s_setprio(1); MFMA_Q(0, 1); __builtin_amdgcn_s_setprio(0);
        BAR();
        // φ6: Q(1,1); reads A1.mh1; stage B(u1).h0
        READ_A(1, 1);
        if (i < 15) STAGE_B(1, 0, u1);
        BAR(); LGKM0();
        __builtin_amdgcn_s_setprio(1); MFMA_Q(1, 1); __builtin_amdgcn_s_setprio(0);
        BAR();
        // φ7: Q(1,0); stage B(u1).h1; counted vmcnt
        if (i < 15) STAGE_B(1, 1, u1);
        BAR(); LGKM0();
        __builtin_amdgcn_s_setprio(1); MFMA_Q(1, 0); __builtin_amdgcn_s_setprio(0);
        if (i < 15) { VM4(); }
        BAR();
    }

    // epilogue: C/D layout col=l16 (n), row=quad*4+reg (b); scale by mask[col]
#pragma unroll
    for (int nf = 0; nf < 4; ++nf) {
        int col = nRow0 + wn * 64 + nf * 16 + l16;
        float mv = maskF[col];
#pragma unroll
        for (int mi = 0; mi < 8; ++mi) {
            int rbase = bRow0 + wm * 128 + mi * 16 + quad * 4;
#pragma unroll
            for (int r = 0; r < 4; ++r)
                out[(size_t)(rbase + r) * N_ROWS + col] = acc[mi][nf][r] * mv;
        }
    }
}

// ---- Kernel F-B (fallback, small ws): compacted-list GEMM from R1 ----
__launch_bounds__(256, 2)
__global__ void gemm_kernel(const float* __restrict__ x,
                            const float* __restrict__ W,
                            const int* __restrict__ count,
                            const int* __restrict__ list,
                            float* __restrict__ out) {
    int cnt = *count;
    int jBase = blockIdx.y * 64;
    if (jBase >= cnt) return;
    int bRow0 = blockIdx.x * 128;

    __shared__ short xT[128 * 80];
    __shared__ short wT[64 * 80];

    int tid  = threadIdx.x;
    int wave = tid >> 6, lane = tid & 63;
    int quad = lane >> 4, l16 = lane & 15;

    int wrow_ids[4];
#pragma unroll
    for (int i = 0; i < 4; ++i) {
        int idx = tid + i * 256;
        int j = jBase + (idx >> 4);
        wrow_ids[i] = list[j < cnt ? j : (cnt - 1)];
    }

    f32x4 acc[2][4];
#pragma unroll
    for (int mi = 0; mi < 2; ++mi)
#pragma unroll
        for (int nf = 0; nf < 4; ++nf)
            acc[mi][nf] = (f32x4){0.f, 0.f, 0.f, 0.f};

    for (int k0 = 0; k0 < D_DIM; k0 += 64) {
        __syncthreads();
#pragma unroll
        for (int i = 0; i < 8; ++i) {
            int idx = tid + i * 256;
            int r = idx >> 4, kq = idx & 15;
            float4 v = *(const float4*)(x + (size_t)(bRow0 + r) * D_DIM + k0 + kq * 4);
            ushort4 b;
            b.x = f2bf(v.x); b.y = f2bf(v.y); b.z = f2bf(v.z); b.w = f2bf(v.w);
            *(ushort4*)(&xT[r * 80 + kq * 4]) = b;
        }
#pragma unroll
        for (int i = 0; i < 4; ++i) {
            int idx = tid + i * 256;
            int r = idx >> 4, kq = idx & 15;
            float4 v = *(const float4*)(W + (size_t)wrow_ids[i] * D_DIM + k0 + kq * 4);
            ushort4 b;
            b.x = f2bf(v.x); b.y = f2bf(v.y); b.z = f2bf(v.z); b.w = f2bf(v.w);
            *(ushort4*)(&wT[r * 80 + kq * 4]) = b;
        }
        __syncthreads();
#pragma unroll
        for (int kk = 0; kk < 64; kk += 32) {
            bf16x8 a0 = *(const bf16x8*)(&xT[(wave * 32 + l16) * 80 + kk + quad * 8]);
            bf16x8 a1 = *(const bf16x8*)(&xT[(wave * 32 + 16 + l16) * 80 + kk + quad * 8]);
#pragma unroll
            for (int nf = 0; nf < 4; ++nf) {
                bf16x8 bv = *(const bf16x8*)(&wT[(nf * 16 + l16) * 80 + kk + quad * 8]);
                acc[0][nf] = __builtin_amdgcn_mfma_f32_16x16x32_bf16(a0, bv, acc[0][nf], 0, 0, 0);
                acc[1][nf] = __builtin_amdgcn_mfma_f32_16x16x32_bf16(a1, bv, acc[1][nf], 0, 0, 0);
            }
        }
    }

#pragma unroll
    for (int nf = 0; nf < 4; ++nf) {
        int j = jBase + nf * 16 + l16;
        if (j < cnt) {
            int col = list[j];
#pragma unroll
            for (int mi = 0; mi < 2; ++mi) {
                int rbase = bRow0 + wave * 32 + mi * 16 + quad * 4;
#pragma unroll
                for (int r = 0; r < 4; ++r)
                    out[(size_t)(rbase + r) * N_ROWS + col] = acc[mi][nf][r];
            }
        }
    }
}

extern "C" void kernel_launch(void* const* d_in, const int* in_sizes, int n_in,
                              void* d_out, int out_size, void* d_ws, size_t ws_size,
                              hipStream_t stream) {
    const float* x = (const float*)d_in[0];
    const float* W = (const float*)d_in[1];
    const float* a = (const float*)d_in[2];
    float* out = (float*)d_out;
    char* ws = (char*)d_ws;

    double* rowSumSq = (double*)(ws + WS_ROWSUMSQ);
    double* rowDotA  = (double*)(ws + WS_ROWDOTA);
    double* colsumD  = (double*)(ws + WS_PARTIAL);
    double* maxSS    = (double*)(ws + WS_MAXSS);
    int*    qBucket  = (int*)(ws + WS_QBUCKET);
    int*    count    = (int*)(ws + WS_COUNT);
    int*    list     = (int*)(ws + WS_LIST);
    float*  maskF    = (float*)(ws + WS_MASKF);
    int*    flags    = (int*)(ws + WS_FLAGS);
    unsigned short* xb = (unsigned short*)(ws + WS_XB);
    unsigned short* wb = (unsigned short*)(ws + WS_WB);

    bool pathA = (ws_size >= WS_A_NEED);

    hipMemsetAsync(count, 0, sizeof(int), stream);
    hipMemsetAsync(flags, 0, 256 * sizeof(int), stream);
    hipMemsetAsync(maxSS, 0, sizeof(double), stream);          // +0.0 bits
    hipMemsetAsync(colsumD, 0, D_DIM * sizeof(double), stream);

    // Single pass over W: stats + bf16 emit (no atomics).
    rowstats_kernel<<<N_ROWS / 8, 256, 0, stream>>>(
        W, a, rowSumSq, rowDotA, pathA ? wb : (unsigned short*)0);
    maxred_kernel<<<N_ROWS / 1024, 1024, 0, stream>>>(
        rowSumSq, (unsigned long long*)maxSS);
    colsum_kernel<<<dim3(D_DIM / 256, 16), 256, 0, stream>>>(x, colsumD);
    qhash_kernel<<<1, 256, 0, stream>>>(colsumD, a, qBucket);
    mask_kernel<<<N_ROWS / 256, 256, 0, stream>>>(rowSumSq, rowDotA, maxSS, qBucket,
                                                  a, count, list, maskF, flags);

    if (pathA) {
        convx_kernel<<<(B_ROWS * (D_DIM / 8)) / 256, 256, 0, stream>>>(x, xb);
        gemm_256<<<dim3(B_ROWS / 256, N_ROWS / 256), 512, 0, stream>>>(
            xb, wb, flags, maskF, out);
    } else {
        // Path B: R1 fallback (fused-conversion compacted GEMM).
        hipMemsetAsync(out, 0, (size_t)out_size * sizeof(float), stream);
        gemm_kernel<<<dim3(B_ROWS / 128, N_ROWS / 64), 256, 0, stream>>>(x, W, count, list, out);
    }
}

// Round 4
// 759.818 us; speedup vs baseline: 1.4136x; 1.0367x over previous
//
#include <hip/hip_runtime.h>

// ALSH masked linear: out[B,N] = x @ (W * mask)^T, mask from bucket match.
// B=2048, D=2048, N=32768, M_AUG=5, TABLE=64, R=4.0, U=0.83.
// Mask is ~all-N -> dense bf16 GEMM (256x256 8-phase counted-vmcnt).
// R5: - gemm LDS swizzle upgraded 1-bit -> 3-bit: rows are 128 B (== 0 mod
//       bank wrap) so bank = f(col) only; frag reads hit 4/8 16B-slots ->
//       2x bank oversubscription with the 1-bit XOR (measured 2.5e7 conflict
//       cycles). col ^= (row&7)<<4 spreads all 8 slots -> wave64 minimum.
//       Applied BOTH sides: pre-swizzled global source for global_load_lds
//       (linear LDS dest) + per-kb XOR on ds_read (bit 6 overlaps kb*64).
//     - rowstats rewritten block-per-row streaming (256 thr x 8 elem): MLP
//       from occupancy, not fp64-chained ILP (was latency-bound).

#define D_DIM 2048
#define N_ROWS 32768
#define B_ROWS 2048
#define M_AUG_C 5
#define TBL 64
#define RBIN 4.0
#define USC 0.83

typedef short bf16x8 __attribute__((ext_vector_type(8)));
typedef float f32x4 __attribute__((ext_vector_type(4)));

// ---- workspace layout (bytes) ----
#define WS_ROWSUMSQ 0                       // double[N]      256 KB
#define WS_ROWDOTA  262144                  // double[N]      256 KB
#define WS_PARTIAL  524288                  // double[D]      16 KB (colsums)
#define WS_MAXSS    786432                  // double
#define WS_QBUCKET  786440                  // int
#define WS_COUNT    786444                  // int
#define WS_LIST     786448                  // int[N]         128 KB
#define WS_MASKF    917520                  // float[N]       128 KB
#define WS_FLAGS    1048592                 // int[256]       1 KB
#define WS_XB       1114112                 // bf16[B*D]      8 MB
#define WS_WB       9502720                 // bf16[N*D]      128 MB
#define WS_A_NEED   143720448ull            // end of WB

__device__ __forceinline__ unsigned short f2bf(float f) {
    unsigned int u = __builtin_bit_cast(unsigned int, f);
    u += 0x7fffu + ((u >> 16) & 1u);   // round-to-nearest-even
    return (unsigned short)(u >> 16);
}

typedef const __attribute__((address_space(1))) unsigned int* as1_u32p;
typedef __attribute__((address_space(3))) unsigned int* as3_u32p;

__device__ __forceinline__ void gload16(const unsigned short* g, unsigned short* l) {
    __builtin_amdgcn_global_load_lds((as1_u32p)(const void*)g, (as3_u32p)(void*)l,
                                     16, 0, 0);
}

// ---- Kernel A: per-row sum(W^2), dot(W_row, a[:D]) (fp64), bf16(W) emit.
// Block-per-row streaming: 256 threads x 8 contiguous elems = one row.
// MLP comes from many resident waves (convx-style), not per-thread ILP.
__global__ void rowstats_kernel(const float* __restrict__ W,
                                const float* __restrict__ a,
                                double* __restrict__ rowSumSq,
                                double* __restrict__ rowDotA,
                                unsigned short* __restrict__ wb) {
    int row = blockIdx.x;
    int tid = threadIdx.x;
    int col = tid * 8;
    const float* wr = W + (size_t)row * D_DIM + col;
    float4 v0 = *(const float4*)(wr);
    float4 v1 = *(const float4*)(wr + 4);
    float4 a0 = *(const float4*)(a + col);
    float4 a1 = *(const float4*)(a + col + 4);
    if (wb) {
        ushort4 p0, p1;
        p0.x = f2bf(v0.x); p0.y = f2bf(v0.y); p0.z = f2bf(v0.z); p0.w = f2bf(v0.w);
        p1.x = f2bf(v1.x); p1.y = f2bf(v1.y); p1.z = f2bf(v1.z); p1.w = f2bf(v1.w);
        unsigned short* wo = wb + (size_t)row * D_DIM + col;
        *(ushort4*)(wo)     = p0;
        *(ushort4*)(wo + 4) = p1;
    }
    double ss = (double)v0.x * v0.x + (double)v0.y * v0.y + (double)v0.z * v0.z + (double)v0.w * v0.w
              + (double)v1.x * v1.x + (double)v1.y * v1.y + (double)v1.z * v1.z + (double)v1.w * v1.w;
    double da = (double)v0.x * a0.x + (double)v0.y * a0.y + (double)v0.z * a0.z + (double)v0.w * a0.w
              + (double)v1.x * a1.x + (double)v1.y * a1.y + (double)v1.z * a1.z + (double)v1.w * a1.w;
    for (int off = 32; off > 0; off >>= 1) {
        ss += __shfl_down(ss, off);
        da += __shfl_down(da, off);
    }
    __shared__ double sss[4], sda[4];
    int wave = tid >> 6, lane = tid & 63;
    if (lane == 0) { sss[wave] = ss; sda[wave] = da; }
    __syncthreads();
    if (tid == 0) {
        rowSumSq[row] = sss[0] + sss[1] + sss[2] + sss[3];
        rowDotA[row]  = sda[0] + sda[1] + sda[2] + sda[3];
    }
}

// ---- Kernel B: max over rowSumSq. 32 blocks, one atomicMax each (ss >= 0,
// so IEEE order == unsigned-int order on the bit pattern). ----
__global__ void maxred_kernel(const double* __restrict__ rowSumSq,
                              unsigned long long* __restrict__ maxBits) {
    int i = blockIdx.x * 1024 + threadIdx.x;
    double m = rowSumSq[i];
    for (int off = 32; off > 0; off >>= 1) m = fmax(m, __shfl_down(m, off));
    __shared__ double sm[16];
    int wave = threadIdx.x >> 6, lane = threadIdx.x & 63;
    if (lane == 0) sm[wave] = m;
    __syncthreads();
    if (threadIdx.x == 0) {
        double mm = sm[0];
#pragma unroll
        for (int k = 1; k < 16; ++k) mm = fmax(mm, sm[k]);
        atomicMax(maxBits, (unsigned long long)__double_as_longlong(mm));
    }
}

// ---- Kernel C1: column sums of x via fp64 atomicAdd (16-way contention) ----
__global__ void colsum_kernel(const float* __restrict__ x,
                              double* __restrict__ colsumD) {
    int col   = blockIdx.x * 256 + threadIdx.x;
    int chunk = blockIdx.y;
    const float* xp = x + (size_t)chunk * 128 * D_DIM + col;
    double s = 0.0;
#pragma unroll 8
    for (int b = 0; b < 128; ++b) s += (double)xp[(size_t)b * D_DIM];
    atomicAdd(&colsumD[col], s);
}

// ---- Kernel C2: query bucket from finished column sums (16 KB read) ----
__global__ void qhash_kernel(const double* __restrict__ colsumD,
                             const float* __restrict__ a,
                             int* __restrict__ qBucket) {
    __shared__ double s_ssq[256], s_dta[256];
    int tid = threadIdx.x;
    double ssq = 0.0, dta = 0.0;
    for (int c = tid; c < D_DIM; c += 256) {
        double cs = colsumD[c];
        ssq += cs * cs;
        dta += cs * (double)a[c];
    }
    s_ssq[tid] = ssq; s_dta[tid] = dta;
    __syncthreads();
    for (int s = 128; s > 0; s >>= 1) {
        if (tid < s) { s_ssq[tid] += s_ssq[tid + s]; s_dta[tid] += s_dta[tid + s]; }
        __syncthreads();
    }
    if (tid == 0) {
        double dq = s_dta[0] / sqrt(s_ssq[0]);
        double aug = 0.0;
        for (int i = 0; i < M_AUG_C; ++i) aug += 0.5 * (double)a[D_DIM + i];
        double h = floor((dq + aug) / RBIN);
        double m = fmod(h, (double)TBL);
        if (m < 0.0) m += (double)TBL;
        *qBucket = (int)m;
    }
}

// ---- Kernel D: row buckets vs query; emit mask float, tile flags, compact list ----
__global__ void mask_kernel(const double* __restrict__ rowSumSq,
                            const double* __restrict__ rowDotA,
                            const double* __restrict__ maxSS,
                            const int* __restrict__ qBucket,
                            const float* __restrict__ a,
                            int* __restrict__ count,
                            int* __restrict__ list,
                            float* __restrict__ maskF,
                            int* __restrict__ flags) {
    int n = blockIdx.x * 256 + threadIdx.x;
    double s  = USC / sqrt(*maxSS);
    double n2 = s * s * rowSumSq[n];
    double acc = s * rowDotA[n];
    double p = n2;
#pragma unroll
    for (int i = 0; i < M_AUG_C; ++i) {    // powers n2^(2^i), successive squaring
        acc += p * (double)a[D_DIM + i];
        p = p * p;
    }
    double h = floor(acc / RBIN);
    double m = fmod(h, (double)TBL);
    if (m < 0.0) m += (double)TBL;
    bool active = ((int)m == *qBucket);
    maskF[n] = active ? 1.f : 0.f;
    if (active) {
        int pos = atomicAdd(count, 1);
        list[pos] = n;
        atomicOr(&flags[n >> 7], 1);
    }
}

// ---- Kernel E2: x -> bf16 ----
__global__ void convx_kernel(const float* __restrict__ x,
                             unsigned short* __restrict__ xb) {
    size_t e = ((size_t)blockIdx.x * 256 + threadIdx.x) * 8;
    float4 v0 = *(const float4*)(x + e);
    float4 v1 = *(const float4*)(x + e + 4);
    ushort4 p0, p1;
    p0.x = f2bf(v0.x); p0.y = f2bf(v0.y); p0.z = f2bf(v0.z); p0.w = f2bf(v0.w);
    p1.x = f2bf(v1.x); p1.y = f2bf(v1.y); p1.z = f2bf(v1.z); p1.w = f2bf(v1.w);
    *(ushort4*)(xb + e)     = p0;
    *(ushort4*)(xb + e + 4) = p1;
}

// ======== Kernel F-A: 256x256 8-phase counted-vmcnt bf16 GEMM ========
// 8 waves (2M x 4N), BK=64, two K-tiles per 8-phase iteration.
// LDS: [parity][op A/B][half 128 rows][128 rows x 64 cols bf16] = 128 KiB.
// 3-bit swizzle: logical k-byte kc of row r lives at physical kc ^ ((r&7)<<4).
// Write side: linear LDS dest (global_load_lds req) + pre-swizzled global src.
// Read side: per-kb XOR (kb*64 sets bit 6, which the XOR touches).
// Raw s_barrier everywhere (no vmcnt drain); vmcnt(4) at phases 3 and 7 only.

#define BAR() do { asm volatile("" ::: "memory"); \
                   __builtin_amdgcn_s_barrier(); \
                   asm volatile("" ::: "memory"); } while (0)
#define LGKM0() do { asm volatile("s_waitcnt lgkmcnt(0)" ::: "memory"); \
                     __builtin_amdgcn_sched_barrier(0); } while (0)
#define VM4() asm volatile("s_waitcnt vmcnt(4)" ::: "memory")
#define VM0() asm volatile("s_waitcnt vmcnt(0)" ::: "memory")
#define VM8() asm volatile("s_waitcnt vmcnt(8)" ::: "memory")

#define READ_A(P, MH) do { _Pragma("unroll") \
    for (int mi = 0; mi < 4; ++mi) { \
        aF[mi][0] = *(const bf16x8*)(aB##P + ((MH)*4 + mi) * 1024 + kOff0); \
        aF[mi][1] = *(const bf16x8*)(aB##P + ((MH)*4 + mi) * 1024 + kOff1); } } while (0)

#define READ_B(P, NH) do { _Pragma("unroll") \
    for (int nf = 0; nf < 2; ++nf) { \
        bF[(NH)*2 + nf][0] = *(const bf16x8*)(bB##P + ((NH)*2 + nf) * 1024 + kOff0); \
        bF[(NH)*2 + nf][1] = *(const bf16x8*)(bB##P + ((NH)*2 + nf) * 1024 + kOff1); } } while (0)

#define STAGE_A(P, H, T) do { \
    gload16(xg0 + (size_t)((H)*128    ) * D_DIM + (T)*64, &lds[P][0][H][wid*1024      ]); \
    gload16(xg0 + (size_t)((H)*128 + 8) * D_DIM + (T)*64, &lds[P][0][H][wid*1024 + 512]); } while (0)

#define STAGE_B(P, H, T) do { \
    gload16(wg0 + (size_t)((H)*128    ) * D_DIM + (T)*64, &lds[P][1][H][wid*1024      ]); \
    gload16(wg0 + (size_t)((H)*128 + 8) * D_DIM + (T)*64, &lds[P][1][H][wid*1024 + 512]); } while (0)

#define MFMA_Q(MH, NH) do { _Pragma("unroll") \
    for (int mi = 0; mi < 4; ++mi) { _Pragma("unroll") \
    for (int nf = 0; nf < 2; ++nf) { _Pragma("unroll") \
    for (int kb = 0; kb < 2; ++kb) { \
        acc[(MH)*4 + mi][(NH)*2 + nf] = __builtin_amdgcn_mfma_f32_16x16x32_bf16( \
            aF[mi][kb], bF[(NH)*2 + nf][kb], acc[(MH)*4 + mi][(NH)*2 + nf], 0, 0, 0); \
    } } } } while (0)

__launch_bounds__(512, 2)
__global__ void gemm_256(const unsigned short* __restrict__ xb,
                         const unsigned short* __restrict__ wb,
                         const int* __restrict__ flags,
                         const float* __restrict__ maskF,
                         float* __restrict__ out) {
    int bRow0 = blockIdx.x * 256;
    int nRow0 = blockIdx.y * 256;
    int tid = threadIdx.x;

    if ((flags[blockIdx.y * 2] | flags[blockIdx.y * 2 + 1]) == 0) {
#pragma unroll
        for (int i = 0; i < 32; ++i) {
            int idx = tid + i * 512;
            int r = idx >> 6, c = idx & 63;
            *(float4*)(out + (size_t)(bRow0 + r) * N_ROWS + nRow0 + c * 4) =
                float4{0.f, 0.f, 0.f, 0.f};
        }
        return;
    }

    __shared__ __align__(16) unsigned short lds[2][2][2][128 * 64];  // 128 KiB

    int wid  = tid >> 6, lane = tid & 63;
    int l16  = lane & 15, quad = lane >> 4;
    int wm   = wid >> 2,  wn   = wid & 3;

    // staging: lane l of call c writes LDS linear (wid*2+c)*1024B + l*16B
    //   -> dest row (wid*2+c)*8 + l>>3 (row&7 = l>>3), col byte (l&7)*16.
    //   Source pre-swizzled: that slot holds logical kc = ((l&7)*16) ^ ((l>>3)<<4).
    int srow8 = lane >> 3;
    int gcolb = (((lane & 7) ^ (lane >> 3)) * 16);   // bytes, bits 4-6 only
    const unsigned short* xg0 = xb + (size_t)(bRow0 + wid * 16 + srow8) * D_DIM + (gcolb >> 1);
    const unsigned short* wg0 = wb + (size_t)(nRow0 + wid * 16 + srow8) * D_DIM + (gcolb >> 1);

    // fragment-read: row&7 = l16&7; logical kc = quad*16 + kb*64; physical
    // offset = kc ^ ((l16&7)<<4), computed per kb (bit-6 overlap). In shorts:
    const int kOff0 = (((quad * 16)      ^ ((l16 & 7) << 4)) >> 1);
    const int kOff1 = (((quad * 16 + 64) ^ ((l16 & 7) << 4)) >> 1);

    const unsigned short* aB0 = &lds[0][0][wm][0] + l16 * 64;
    const unsigned short* aB1 = &lds[1][0][wm][0] + l16 * 64;
    const unsigned short* bB0 = &lds[0][1][wn >> 1][0] + (wn & 1) * 4096 + l16 * 64;
    const unsigned short* bB1 = &lds[1][1][wn >> 1][0] + (wn & 1) * 4096 + l16 * 64;

    f32x4 acc[8][4];
#pragma unroll
    for (int mi = 0; mi < 8; ++mi)
#pragma unroll
        for (int nf = 0; nf < 4; ++nf)
            acc[mi][nf] = (f32x4){0.f, 0.f, 0.f, 0.f};

    bf16x8 aF[4][2], bF[4][2];

    // ---- prologue: stage tiles 0 (parity 0) and 1 (parity 1); tile0 ready ----
    STAGE_A(0, 0, 0); STAGE_A(0, 1, 0); STAGE_B(0, 0, 0); STAGE_B(0, 1, 0);
    STAGE_A(1, 0, 1); STAGE_A(1, 1, 1); STAGE_B(1, 0, 1); STAGE_B(1, 1, 1);
    VM8();
    BAR();

    // ---- main: 16 iterations x (2 K-tiles, 8 phases). NT = 32 K-tiles. ----
#pragma unroll 1
    for (int i = 0; i < 16; ++i) {
        const int t1 = 2 * i + 1;
        const int u0 = 2 * i + 2;   // staged this iter, parity 0
        const int u1 = 2 * i + 3;   // staged this iter, parity 1

        // φ0: tile t0 Q(0,0); reads A0.mh0 + B0.nh0; stage A(t1).h0
        READ_A(0, 0);
        READ_B(0, 0);
        if (i > 0) STAGE_A(1, 0, t1);
        BAR(); LGKM0();
        __builtin_amdgcn_s_setprio(1); MFMA_Q(0, 0); __builtin_amdgcn_s_setprio(0);
        BAR();
        // φ1: Q(0,1); reads B0.nh1; stage A(t1).h1
        READ_B(0, 1);
        if (i > 0) STAGE_A(1, 1, t1);
        BAR(); LGKM0();
        __builtin_amdgcn_s_setprio(1); MFMA_Q(0, 1); __builtin_amdgcn_s_setprio(0);
        BAR();
        // φ2: Q(1,1); reads A0.mh1; stage B(u0).h0
        READ_A(0, 1);
        if (i < 15) STAGE_B(0, 0, u0);
        BAR(); LGKM0();
        __builtin_amdgcn_s_setprio(1); MFMA_Q(1, 1); __builtin_amdgcn_s_setprio(0);
        BAR();
        // φ3: Q(1,0); stage B(u0).h1; counted vmcnt
        if (i < 15) STAGE_B(0, 1, u0);
        BAR(); LGKM0();
        __builtin_amdgcn_s_setprio(1); MFMA_Q(1, 0); __builtin_amdgcn_s_setprio(0);
        if (i < 15) { VM4(); } else { VM0(); }
        BAR();
        // φ4: tile t1 Q(0,0); reads A1.mh0 + B1.nh0; stage A(u0).h0
        READ_A(1, 0);
        READ_B(1, 0);
        if (i < 15) STAGE_A(0, 0, u0);
        BAR(); LGKM0();
        __builtin_amdgcn_s_setprio(1); MFMA_Q(0, 0); __builtin_amdgcn_s_setprio(0);
        BAR();
        // φ5: Q(0,1); reads B1.nh1; stage A(u0).h1
        READ_B(1, 1);
        if (i < 15) STAGE_A(0, 1, u0);
        BAR(); LGKM0();
        __builtin_amdgcn_s_setprio(1); MFMA_Q(0, 1); __builtin_amdgcn_s_setprio(0);
        BAR();
        // φ6: Q(1,1); reads A1.mh1; stage B(u1).h0
        READ_A(1, 1);
        if (i < 15) STAGE_B(1, 0, u1);
        BAR(); LGKM0();
        __builtin_amdgcn_s_setprio(1); MFMA_Q(1, 1); __builtin_amdgcn_s_setprio(0);
        BAR();
        // φ7: Q(1,0); stage B(u1).h1; counted vmcnt
        if (i < 15) STAGE_B(1, 1, u1);
        BAR(); LGKM0();
        __builtin_amdgcn_s_setprio(1); MFMA_Q(1, 0); __builtin_amdgcn_s_setprio(0);
        if (i < 15) { VM4(); }
        BAR();
    }

    // epilogue: C/D layout col=l16 (n), row=quad*4+reg (b); scale by mask[col]
#pragma unroll
    for (int nf = 0; nf < 4; ++nf) {
        int col = nRow0 + wn * 64 + nf * 16 + l16;
        float mv = maskF[col];
#pragma unroll
        for (int mi = 0; mi < 8; ++mi) {
            int rbase = bRow0 + wm * 128 + mi * 16 + quad * 4;
#pragma unroll
            for (int r = 0; r < 4; ++r)
                out[(size_t)(rbase + r) * N_ROWS + col] = acc[mi][nf][r] * mv;
        }
    }
}

// ---- Kernel F-B (fallback, small ws): compacted-list GEMM from R1 ----
__launch_bounds__(256, 2)
__global__ void gemm_kernel(const float* __restrict__ x,
                            const float* __restrict__ W,
                            const int* __restrict__ count,
                            const int* __restrict__ list,
                            float* __restrict__ out) {
    int cnt = *count;
    int jBase = blockIdx.y * 64;
    if (jBase >= cnt) return;
    int bRow0 = blockIdx.x * 128;

    __shared__ short xT[128 * 80];
    __shared__ short wT[64 * 80];

    int tid  = threadIdx.x;
    int wave = tid >> 6, lane = tid & 63;
    int quad = lane >> 4, l16 = lane & 15;

    int wrow_ids[4];
#pragma unroll
    for (int i = 0; i < 4; ++i) {
        int idx = tid + i * 256;
        int j = jBase + (idx >> 4);
        wrow_ids[i] = list[j < cnt ? j : (cnt - 1)];
    }

    f32x4 acc[2][4];
#pragma unroll
    for (int mi = 0; mi < 2; ++mi)
#pragma unroll
        for (int nf = 0; nf < 4; ++nf)
            acc[mi][nf] = (f32x4){0.f, 0.f, 0.f, 0.f};

    for (int k0 = 0; k0 < D_DIM; k0 += 64) {
        __syncthreads();
#pragma unroll
        for (int i = 0; i < 8; ++i) {
            int idx = tid + i * 256;
            int r = idx >> 4, kq = idx & 15;
            float4 v = *(const float4*)(x + (size_t)(bRow0 + r) * D_DIM + k0 + kq * 4);
            ushort4 b;
            b.x = f2bf(v.x); b.y = f2bf(v.y); b.z = f2bf(v.z); b.w = f2bf(v.w);
            *(ushort4*)(&xT[r * 80 + kq * 4]) = b;
        }
#pragma unroll
        for (int i = 0; i < 4; ++i) {
            int idx = tid + i * 256;
            int r = idx >> 4, kq = idx & 15;
            float4 v = *(const float4*)(W + (size_t)wrow_ids[i] * D_DIM + k0 + kq * 4);
            ushort4 b;
            b.x = f2bf(v.x); b.y = f2bf(v.y); b.z = f2bf(v.z); b.w = f2bf(v.w);
            *(ushort4*)(&wT[r * 80 + kq * 4]) = b;
        }
        __syncthreads();
#pragma unroll
        for (int kk = 0; kk < 64; kk += 32) {
            bf16x8 a0 = *(const bf16x8*)(&xT[(wave * 32 + l16) * 80 + kk + quad * 8]);
            bf16x8 a1 = *(const bf16x8*)(&xT[(wave * 32 + 16 + l16) * 80 + kk + quad * 8]);
#pragma unroll
            for (int nf = 0; nf < 4; ++nf) {
                bf16x8 bv = *(const bf16x8*)(&wT[(nf * 16 + l16) * 80 + kk + quad * 8]);
                acc[0][nf] = __builtin_amdgcn_mfma_f32_16x16x32_bf16(a0, bv, acc[0][nf], 0, 0, 0);
                acc[1][nf] = __builtin_amdgcn_mfma_f32_16x16x32_bf16(a1, bv, acc[1][nf], 0, 0, 0);
            }
        }
    }

#pragma unroll
    for (int nf = 0; nf < 4; ++nf) {
        int j = jBase + nf * 16 + l16;
        if (j < cnt) {
            int col = list[j];
#pragma unroll
            for (int mi = 0; mi < 2; ++mi) {
                int rbase = bRow0 + wave * 32 + mi * 16 + quad * 4;
#pragma unroll
                for (int r = 0; r < 4; ++r)
                    out[(size_t)(rbase + r) * N_ROWS + col] = acc[mi][nf][r];
            }
        }
    }
}

extern "C" void kernel_launch(void* const* d_in, const int* in_sizes, int n_in,
                              void* d_out, int out_size, void* d_ws, size_t ws_size,
                              hipStream_t stream) {
    const float* x = (const float*)d_in[0];
    const float* W = (const float*)d_in[1];
    const float* a = (const float*)d_in[2];
    float* out = (float*)d_out;
    char* ws = (char*)d_ws;

    double* rowSumSq = (double*)(ws + WS_ROWSUMSQ);
    double* rowDotA  = (double*)(ws + WS_ROWDOTA);
    double* colsumD  = (double*)(ws + WS_PARTIAL);
    double* maxSS    = (double*)(ws + WS_MAXSS);
    int*    qBucket  = (int*)(ws + WS_QBUCKET);
    int*    count    = (int*)(ws + WS_COUNT);
    int*    list     = (int*)(ws + WS_LIST);
    float*  maskF    = (float*)(ws + WS_MASKF);
    int*    flags    = (int*)(ws + WS_FLAGS);
    unsigned short* xb = (unsigned short*)(ws + WS_XB);
    unsigned short* wb = (unsigned short*)(ws + WS_WB);

    bool pathA = (ws_size >= WS_A_NEED);

    hipMemsetAsync(count, 0, sizeof(int), stream);
    hipMemsetAsync(flags, 0, 256 * sizeof(int), stream);
    hipMemsetAsync(maxSS, 0, sizeof(double), stream);          // +0.0 bits
    hipMemsetAsync(colsumD, 0, D_DIM * sizeof(double), stream);

    // Single pass over W: stats + bf16 emit (block-per-row streaming).
    rowstats_kernel<<<N_ROWS, 256, 0, stream>>>(
        W, a, rowSumSq, rowDotA, pathA ? wb : (unsigned short*)0);
    maxred_kernel<<<N_ROWS / 1024, 1024, 0, stream>>>(
        rowSumSq, (unsigned long long*)maxSS);
    colsum_kernel<<<dim3(D_DIM / 256, 16), 256, 0, stream>>>(x, colsumD);
    qhash_kernel<<<1, 256, 0, stream>>>(colsumD, a, qBucket);
    mask_kernel<<<N_ROWS / 256, 256, 0, stream>>>(rowSumSq, rowDotA, maxSS, qBucket,
                                                  a, count, list, maskF, flags);

    if (pathA) {
        convx_kernel<<<(B_ROWS * (D_DIM / 8)) / 256, 256, 0, stream>>>(x, xb);
        gemm_256<<<dim3(B_ROWS / 256, N_ROWS / 256), 512, 0, stream>>>(
            xb, wb, flags, maskF, out);
    } else {
        // Path B: R1 fallback (fused-conversion compacted GEMM).
        hipMemsetAsync(out, 0, (size_t)out_size * sizeof(float), stream);
        gemm_kernel<<<dim3(B_ROWS / 128, N_ROWS / 64), 256, 0, stream>>>(x, W, count, list, out);
    }
}